// Round 1
// baseline (53.144 us; speedup 1.0000x reference)
//
#include <hip/hip_runtime.h>
#include <hip/hip_bf16.h>

// Problem constants
#define B 64
#define D 1024
#define H 1024
#define C 32           // number of chunks along D
#define L (D / C)      // chunk length = 32

// ---------------------------------------------------------------------------
// Kernel 0: transpose in_W [H, D] -> Wt [D, H]
// ---------------------------------------------------------------------------
__global__ void k_transpose(const float* __restrict__ in, float* __restrict__ out) {
    __shared__ float tile[32][33];
    int bx = blockIdx.x * 32;  // d-range
    int by = blockIdx.y * 32;  // h-range
    int tx = threadIdx.x;      // 0..31
    int ty = threadIdx.y;      // 0..7
    #pragma unroll
    for (int r = 0; r < 32; r += 8)
        tile[ty + r][tx] = in[(by + ty + r) * D + (bx + tx)];
    __syncthreads();
    #pragma unroll
    for (int r = 0; r < 32; r += 8)
        out[(bx + ty + r) * H + (by + tx)] = tile[tx][ty + r];
}

// ---------------------------------------------------------------------------
// Kernel 1: per-chunk rank-1 sums  S[b,c,:] = sum_{j in chunk c} x[b,j]*Wt[j,:]
// block = (b,c), 256 threads, 4 h per thread (float4)
// ---------------------------------------------------------------------------
__global__ void k_chunk_sums(const float* __restrict__ x,
                             const float* __restrict__ Wt,
                             float* __restrict__ S) {
    int b = blockIdx.x / C;
    int c = blockIdx.x % C;
    int tid = threadIdx.x;
    int h0 = tid * 4;

    __shared__ float xs[L];
    if (tid < L) xs[tid] = x[b * D + c * L + tid];
    __syncthreads();

    float4 acc = make_float4(0.f, 0.f, 0.f, 0.f);
    #pragma unroll 4
    for (int j = 0; j < L; ++j) {
        if (xs[j] != 0.f) {  // x is exactly {0,1}
            float4 w = *reinterpret_cast<const float4*>(&Wt[(c * L + j) * H + h0]);
            acc.x += w.x; acc.y += w.y; acc.z += w.z; acc.w += w.w;
        }
    }
    *reinterpret_cast<float4*>(&S[(b * C + c) * H + h0]) = acc;
}

// ---------------------------------------------------------------------------
// Kernel 2: in-place exclusive scan over chunks: S[b,c,h] -> sum_{c'<c} S[b,c',h]
// one thread per (b,h)
// ---------------------------------------------------------------------------
__global__ void k_scan(float* __restrict__ S) {
    int tid = blockIdx.x * blockDim.x + threadIdx.x;  // 0 .. B*H-1
    if (tid >= B * H) return;
    int b = tid / H;
    int h = tid % H;
    float run = 0.f;
    #pragma unroll
    for (int c = 0; c < C; ++c) {
        int idx = (b * C + c) * H + h;
        float v = S[idx];
        S[idx] = run;
        run += v;
    }
}

// ---------------------------------------------------------------------------
// Kernel 3: main NADE chain. block = (b,c), 256 threads, 4 h per thread.
// a (register float4) = in_b + prefix; then 32 serial steps:
//   p_i = sigmoid( sum_h relu(a_h) * h_W[i,h] + h_b[i] );  a += x_i * Wt[i,:]
// ---------------------------------------------------------------------------
__global__ void __launch_bounds__(256)
k_nade_main(const float* __restrict__ x,
            const float* __restrict__ Wt,
            const float* __restrict__ in_b,
            const float* __restrict__ h_W,
            const float* __restrict__ h_b,
            const float* __restrict__ P,   // exclusive chunk prefixes
            float* __restrict__ out) {
    int b = blockIdx.x / C;
    int c = blockIdx.x % C;
    int tid = threadIdx.x;
    int h0 = tid * 4;
    int lane = tid & 63;
    int wave = tid >> 6;

    __shared__ float xs[L];
    __shared__ float partials[8];  // 2 parity slots x 4 waves

    if (tid < L) xs[tid] = x[b * D + c * L + tid];

    float4 a = *reinterpret_cast<const float4*>(&P[(b * C + c) * H + h0]);
    float4 ib = *reinterpret_cast<const float4*>(&in_b[h0]);
    a.x += ib.x; a.y += ib.y; a.z += ib.z; a.w += ib.w;

    __syncthreads();

    for (int il = 0; il < L; ++il) {
        int i = c * L + il;
        float4 w = *reinterpret_cast<const float4*>(&h_W[i * H + h0]);
        float p = fmaxf(a.x, 0.f) * w.x + fmaxf(a.y, 0.f) * w.y +
                  fmaxf(a.z, 0.f) * w.z + fmaxf(a.w, 0.f) * w.w;
        // wave (64-lane) reduction
        #pragma unroll
        for (int off = 32; off > 0; off >>= 1)
            p += __shfl_down(p, off, 64);
        int slot = ((il & 1) << 2) + wave;
        if (lane == 0) partials[slot] = p;
        __syncthreads();
        if (tid == 0) {
            int base = (il & 1) << 2;
            float t = partials[base] + partials[base + 1] +
                      partials[base + 2] + partials[base + 3] + h_b[i];
            out[b * D + i] = 1.0f / (1.0f + expf(-t));
        }
        if (xs[il] != 0.f) {  // x is exactly {0,1}; skip load when 0
            float4 wv = *reinterpret_cast<const float4*>(&Wt[i * H + h0]);
            a.x += wv.x; a.y += wv.y; a.z += wv.z; a.w += wv.w;
        }
    }
}

// ---------------------------------------------------------------------------
extern "C" void kernel_launch(void* const* d_in, const int* in_sizes, int n_in,
                              void* d_out, int out_size, void* d_ws, size_t ws_size,
                              hipStream_t stream) {
    const float* x    = (const float*)d_in[0];  // [B, D]
    const float* in_W = (const float*)d_in[1];  // [H, D]
    const float* in_b = (const float*)d_in[2];  // [H]
    const float* h_W  = (const float*)d_in[3];  // [D, H]
    const float* h_b  = (const float*)d_in[4];  // [D]
    float* out = (float*)d_out;                 // [B, D]

    float* Wt = (float*)d_ws;                   // [D, H]  4 MB
    float* S  = Wt + (size_t)D * H;             // [B, C, H]  8 MB

    // 0: transpose in_W -> Wt
    dim3 tb(32, 8);
    dim3 tg(D / 32, H / 32);
    k_transpose<<<tg, tb, 0, stream>>>(in_W, Wt);

    // 1: chunk sums
    k_chunk_sums<<<B * C, 256, 0, stream>>>(x, Wt, S);

    // 2: exclusive scan over chunks (in place)
    k_scan<<<(B * H + 255) / 256, 256, 0, stream>>>(S);

    // 3: main serial chain
    k_nade_main<<<B * C, 256, 0, stream>>>(x, Wt, in_b, h_W, h_b, S, out);
}